// Round 1
// 511.421 us; speedup vs baseline: 1.0742x; 1.0742x over previous
//
#include <hip/hip_runtime.h>
#include <hip/hip_bf16.h>

// ---------------------------------------------------------------------------
// Swin window MSA, MI355X/gfx950.
// R5: both GEMMs moved from the 128x128 2-barrier-per-K-step structure
// (MfmaUtil 25.8%) to the 256x256 phase-interleaved schedule:
//  - 8 waves (2Mx4N), BK=32, 4-slot LDS ring (128 KiB), 2 K-tiles in flight
//  - counted s_waitcnt vmcnt(8) once per K-tile (never 0 in main loop)
//  - T2 LDS swizzle: linear glds dest + pre-swizzled GLOBAL source
//    (chunk ^= row&3) + same XOR on ds_read address
//  - T5 setprio(1) around each 16-MFMA cluster, raw s_barrier (no vmcnt drain)
//  - T1 XCD-aware blockIdx swizzle, mtile-major (B goes L2-resident)
// qkv planes: [which][w][h][tok][d]. attn out: head-blocked [h][w][tok][d].
// ---------------------------------------------------------------------------

typedef unsigned short u16;
typedef __bf16 bx8 __attribute__((ext_vector_type(8)));
typedef float f4_t __attribute__((ext_vector_type(4)));

#define QKV_ELEMS 33554432ull        // 1024*16*64*32 per Q/K/V plane
#define SCALE 0.17677669529663687f   // 32^-0.5

static __device__ __forceinline__ u16 f2b(float f) {
    return __builtin_bit_cast(u16, (__bf16)f);
}

typedef const unsigned int __attribute__((address_space(1)))* gas_t;
typedef unsigned int __attribute__((address_space(3)))* las_t;
static __device__ __forceinline__ void glds16(const void* g, void* l) {
    __builtin_amdgcn_global_load_lds((gas_t)g, (las_t)l, 16, 0, 0);
}

// ---- prep: x fp32 -> bf16 (8 elems/thread) --------------------------------
__global__ void cvt_k(const float* __restrict__ X, u16* __restrict__ Xb) {
    size_t i = ((size_t)blockIdx.x * 256 + threadIdx.x) * 8;
    float4 v0 = *(const float4*)(X + i);
    float4 v1 = *(const float4*)(X + i + 4);
    ushort4 p0, p1;
    p0.x = f2b(v0.x); p0.y = f2b(v0.y); p0.z = f2b(v0.z); p0.w = f2b(v0.w);
    p1.x = f2b(v1.x); p1.y = f2b(v1.y); p1.z = f2b(v1.z); p1.w = f2b(v1.w);
    *(ushort4*)(Xb + i) = p0;
    *(ushort4*)(Xb + i + 4) = p1;
}

// ---- prep: W (K x N fp32) -> Wt (N x K bf16) ------------------------------
__global__ void wt_k(const float* __restrict__ W, u16* __restrict__ Wt,
                     int K, int N) {
    int idx = blockIdx.x * 256 + threadIdx.x;
    if (idx >= N * K) return;
    int n = idx / K, k = idx - n * K;
    Wt[idx] = f2b(W[(size_t)k * N + n]);
}

// ---- prep: bias_full[h][q][k] = bias_table[rel_index[q*64+k]][h] ----------
__global__ void bias_k(const float* __restrict__ bias_table,
                       const int* __restrict__ rel_index,
                       float* __restrict__ bias_full) {
    int idx = blockIdx.x * 256 + threadIdx.x;   // 16*4096
    int h = idx >> 12, rc = idx & 4095;
    bias_full[idx] = bias_table[rel_index[rc] * 16 + h];
}

// ---- 256x256-tile phase-interleaved GEMM ----------------------------------
// C = A @ Bt^T (+bias), K=512 fixed (NT=16 K-tiles of 32).
// MODE 0: A = xb row-major MxK; out -> QKV planes bf16.
// MODE 1: A = attn head-blocked [h][w][tok][32] (plane h == K-tile h);
//         out -> fp32 rows (N=512).

// one MFMA sub-cluster: a-frag x 4 b-frags
#define MF(av, mt)                                                            \
    acc[mt][0] = __builtin_amdgcn_mfma_f32_16x16x32_bf16(av, b0, acc[mt][0],  \
                                                         0, 0, 0);            \
    acc[mt][1] = __builtin_amdgcn_mfma_f32_16x16x32_bf16(av, b1, acc[mt][1],  \
                                                         0, 0, 0);            \
    acc[mt][2] = __builtin_amdgcn_mfma_f32_16x16x32_bf16(av, b2, acc[mt][2],  \
                                                         0, 0, 0);            \
    acc[mt][3] = __builtin_amdgcn_mfma_f32_16x16x32_bf16(av, b3, acc[mt][3],  \
                                                         0, 0, 0);

// one K-tile = 2 phases. vmcnt ONLY at the tile boundary (phase 2), counted.
#define TILE_STEP(T, DOSTAGE, VMC)                                            \
    {                                                                         \
        const char* aT = ldsA + ((T) & 3) * 16384 + wm * 8192 + foff;         \
        const char* bT = ldsB + ((T) & 3) * 16384 + wn * 4096 + foff;         \
        bx8 b0 = *(const bx8*)(bT);                                           \
        bx8 b1 = *(const bx8*)(bT + 1024);                                    \
        bx8 b2 = *(const bx8*)(bT + 2048);                                    \
        bx8 b3 = *(const bx8*)(bT + 3072);                                    \
        bx8 a0 = *(const bx8*)(aT);                                           \
        bx8 a1 = *(const bx8*)(aT + 1024);                                    \
        bx8 a2 = *(const bx8*)(aT + 2048);                                    \
        bx8 a3 = *(const bx8*)(aT + 3072);                                    \
        if (DOSTAGE) STAGE_A((T) + 3);                                        \
        __builtin_amdgcn_s_barrier();                                         \
        __builtin_amdgcn_s_setprio(1);                                        \
        MF(a0, 0) MF(a1, 1) MF(a2, 2) MF(a3, 3)                               \
        __builtin_amdgcn_s_setprio(0);                                        \
        __builtin_amdgcn_s_barrier();                                         \
        bx8 a4 = *(const bx8*)(aT + 4096);                                    \
        bx8 a5 = *(const bx8*)(aT + 5120);                                    \
        bx8 a6 = *(const bx8*)(aT + 6144);                                    \
        bx8 a7 = *(const bx8*)(aT + 7168);                                    \
        if (DOSTAGE) STAGE_B((T) + 3);                                        \
        if ((VMC) == 8) asm volatile("s_waitcnt vmcnt(8)" ::: "memory");      \
        else if ((VMC) == 4) asm volatile("s_waitcnt vmcnt(4)" ::: "memory"); \
        else if ((VMC) == 0) asm volatile("s_waitcnt vmcnt(0)" ::: "memory"); \
        __builtin_amdgcn_s_barrier();                                         \
        __builtin_amdgcn_s_setprio(1);                                        \
        MF(a4, 4) MF(a5, 5) MF(a6, 6) MF(a7, 7)                               \
        __builtin_amdgcn_s_setprio(0);                                        \
        __builtin_amdgcn_s_barrier();                                         \
    }

template <int MODE>
__global__ __launch_bounds__(512, 2) void gemm256_k(
    const u16* __restrict__ A, const u16* __restrict__ Bt,
    const float* __restrict__ bias, void* __restrict__ Out) {
    extern __shared__ __align__(16) char smem[];   // 131072 B dynamic
    const int tid = threadIdx.x;
    const int wave = tid >> 6, lane = tid & 63;
    const int l16 = lane & 15, quad = lane >> 4;
    const int wm = wave >> 2, wn = wave & 3;       // 2M x 4N wave grid

    // T1: bijective XCD swizzle (nwg % 8 == 0), mtile-major per chunk
    const int NT_COL = (MODE == 0) ? 6 : 2;
    const int NWG = (MODE == 0) ? 1536 : 512;
    const int bid = blockIdx.x;
    const int swz = (bid & 7) * (NWG >> 3) + (bid >> 3);
    const int m0 = (swz / NT_COL) << 8;
    const int n0 = (swz % NT_COL) << 8;

    char* const ldsA = smem;            // 4 slots x 16 KB
    char* const ldsB = smem + 65536;    // 4 slots x 16 KB

    // staging: per call (c=0/1) 512 threads cover 128 rows x 64 B.
    // HW lands lane l at base + l*16 -> row 16*wave + (l>>2), chunk l&3.
    // T2: source chunk pre-swizzled so LDS[row][c] = global[row][c ^ (row&3)].
    const int lr = lane >> 2, lc = lane & 3;
    const int swzc = (lc ^ (lr & 3)) * 8;          // elems
    const int stoff = wave * 1024;                 // wave-uniform LDS base

    const u16* Asrc0;
    const u16* Asrc1;
    if (MODE == 0) {
        const int r0 = m0 + wave * 16 + lr;
        Asrc0 = A + (size_t)r0 * 512 + swzc;
        Asrc1 = Asrc0 + (size_t)128 * 512;
    } else {
        const int r0 = m0 + wave * 16 + lr, r1 = r0 + 128;
        Asrc0 = A + (size_t)(r0 >> 6) * 2048 + (r0 & 63) * 32 + swzc;
        Asrc1 = A + (size_t)(r1 >> 6) * 2048 + (r1 & 63) * 32 + swzc;
    }
    const u16* Bsrc0 = Bt + (size_t)(n0 + wave * 16 + lr) * 512 + swzc;
    const u16* Bsrc1 = Bsrc0 + (size_t)128 * 512;

    auto STAGE_A = [&](int T) {
        char* d = ldsA + (T & 3) * 16384 + stoff;
        if (MODE == 0) {
            glds16(Asrc0 + T * 32, d);
            glds16(Asrc1 + T * 32, d + 8192);
        } else {
            glds16(Asrc0 + (size_t)T * 2097152, d);
            glds16(Asrc1 + (size_t)T * 2097152, d + 8192);
        }
    };
    auto STAGE_B = [&](int T) {
        char* d = ldsB + (T & 3) * 16384 + stoff;
        glds16(Bsrc0 + T * 32, d);
        glds16(Bsrc1 + T * 32, d + 8192);
    };

    // frag read: row = (16-row block)*16 + l16, chunk = quad ^ (row&3)
    const int foff = l16 * 64 + ((quad ^ (l16 & 3)) * 16);

    f4_t acc[8][4];
#pragma unroll
    for (int i = 0; i < 8; ++i)
#pragma unroll
        for (int j = 0; j < 4; ++j) acc[i][j] = (f4_t){0.f, 0.f, 0.f, 0.f};

    // prologue: 3 K-tiles staged; vmcnt(8) retires tile 0 (and A1,B1)
    STAGE_A(0); STAGE_B(0); STAGE_A(1); STAGE_B(1); STAGE_A(2); STAGE_B(2);
    asm volatile("s_waitcnt vmcnt(8)" ::: "memory");
    __builtin_amdgcn_s_barrier();

    for (int T = 0; T < 13; ++T) TILE_STEP(T, true, 8);
    TILE_STEP(13, false, 4);
    TILE_STEP(14, false, 0);
    TILE_STEP(15, false, -1);

    float bv[4];
#pragma unroll
    for (int nt = 0; nt < 4; ++nt) bv[nt] = bias[n0 + wn * 64 + nt * 16 + l16];

    if (MODE == 0) {
        // epilogue: LDS restage -> QKV planes, 1024 B/wave contiguous stores.
        // column layout is [head][which][d]: 96 = 3*32 cols per head.
        u16* c_s = (u16*)smem;          // [128][264] bf16
        u16* qkvp = (u16*)Out;
        const int cg = n0 + wave * 32;
        const int hh = cg / 96;
        const int which = (cg - hh * 96) >> 5;
        u16* plane = qkvp + (size_t)which * QKV_ELEMS + (size_t)hh * 2048;
#pragma unroll
        for (int p = 0; p < 2; ++p) {
            if (wm == p) {
#pragma unroll
                for (int mt = 0; mt < 8; ++mt)
#pragma unroll
                    for (int nt = 0; nt < 4; ++nt)
#pragma unroll
                        for (int i = 0; i < 4; ++i)
                            c_s[(mt * 16 + quad * 4 + i) * 264 +
                                wn * 64 + nt * 16 + l16] =
                                f2b(acc[mt][nt][i] + bv[nt]);
            }
            __syncthreads();
#pragma unroll
            for (int j = 0; j < 8; ++j) {
                int row = j * 16 + (lane >> 2);
                int gm = m0 + p * 128 + row;
                int w_win = gm >> 6, tok = gm & 63;
                uint4 v = *(const uint4*)&c_s[row * 264 + wave * 32 +
                                              (lane & 3) * 8];
                *(uint4*)(plane + (size_t)w_win * 32768 + tok * 32 +
                          (lane & 3) * 8) = v;
            }
            __syncthreads();
        }
    } else {
        // epilogue: fp32 rows, 4 passes of 64 rows, 1024 B/wave stores
        float* c_sf = (float*)smem;     // [64][264] fp32
        float* Of = (float*)Out;
#pragma unroll
        for (int p = 0; p < 4; ++p) {
            if (wm == (p >> 1)) {
                const int mtb = (p & 1) * 4;
#pragma unroll
                for (int mt2 = 0; mt2 < 4; ++mt2)
#pragma unroll
                    for (int nt = 0; nt < 4; ++nt)
#pragma unroll
                        for (int i = 0; i < 4; ++i)
                            c_sf[(mt2 * 16 + quad * 4 + i) * 264 +
                                 wn * 64 + nt * 16 + l16] =
                                acc[mtb + mt2][nt][i] + bv[nt];
            }
            __syncthreads();
#pragma unroll
            for (int j = 0; j < 8; ++j) {
                int flat = tid + 512 * j;           // 64 rows x 64 float4
                int r = flat >> 6, c4 = (flat & 63) * 4;
                float4 v = *(const float4*)&c_sf[r * 264 + c4];
                *(float4*)&Of[(size_t)(m0 + p * 64 + r) * 512 + n0 + c4] = v;
            }
            __syncthreads();
        }
    }
}

// ---- attention: 1 block per (window, head), 4 waves -----------------------
__global__ __launch_bounds__(256) void attn_k(
    const u16* __restrict__ qkv, const float* __restrict__ mask,
    const float* __restrict__ biasf, u16* __restrict__ attn_out) {
    const int bx = blockIdx.x;
    const int w = bx >> 4, h = bx & 15;
    const int wmk = w & 255;  // mask window = b % 256
    const int tid = threadIdx.x;
    const int wave = tid >> 6, lane = tid & 63;
    const int quad = lane >> 4, l16 = lane & 15;

    __shared__ alignas(16) u16 q_s[64 * 40];
    __shared__ alignas(16) u16 k_s[64 * 40];
    __shared__ alignas(16) u16 vT[32 * 72];   // vT[d][tok]
    __shared__ alignas(16) float s_s[64 * 68];
    __shared__ alignas(16) u16 p_s[64 * 72];

    const size_t base = (size_t)((w << 4) + h) * 2048;  // 64*32 per (w,h)
    {
        int tok = tid >> 2, d0 = (tid & 3) * 8;
        uint4 qv = *(const uint4*)(qkv + base + tid * 8);
        *(uint4*)&q_s[tok * 40 + d0] = qv;
        uint4 kv = *(const uint4*)(qkv + QKV_ELEMS + base + tid * 8);
        *(uint4*)&k_s[tok * 40 + d0] = kv;
        uint4 vv = *(const uint4*)(qkv + 2 * QKV_ELEMS + base + tid * 8);
        const u16* pv = (const u16*)&vv;
#pragma unroll
        for (int j = 0; j < 8; ++j) vT[(d0 + j) * 72 + tok] = pv[j];
    }
    __syncthreads();

    // S = Q K^T * scale + bias + mask  (wave -> 16-row strip)
    {
        bx8 a = *(const bx8*)&q_s[(wave * 16 + l16) * 40 + quad * 8];
#pragma unroll
        for (int nt = 0; nt < 4; ++nt) {
            bx8 b = *(const bx8*)&k_s[(nt * 16 + l16) * 40 + quad * 8];
            f4_t acc = (f4_t){0.f, 0.f, 0.f, 0.f};
            acc = __builtin_amdgcn_mfma_f32_16x16x32_bf16(a, b, acc, 0, 0, 0);
#pragma unroll
            for (int i = 0; i < 4; ++i) {
                int r = wave * 16 + quad * 4 + i;
                int c = nt * 16 + l16;
                float s = acc[i] * SCALE + biasf[(h << 12) + (r << 6) + c] +
                          mask[((size_t)wmk * 64 + r) * 64 + c];
                s_s[r * 68 + c] = s;
            }
        }
    }
    __syncthreads();

    // row softmax: 4 threads per row, 16 cols each, shuffle-reduce
    {
        int row = tid >> 2, j = (tid & 3) * 16;
        float mx = -1e30f;
#pragma unroll
        for (int cc = 0; cc < 16; ++cc) mx = fmaxf(mx, s_s[row * 68 + j + cc]);
        mx = fmaxf(mx, __shfl_xor(mx, 1));
        mx = fmaxf(mx, __shfl_xor(mx, 2));
        float e[16], sum = 0.f;
#pragma unroll
        for (int cc = 0; cc < 16; ++cc) {
            e[cc] = __expf(s_s[row * 68 + j + cc] - mx);
            sum += e[cc];
        }
        sum += __shfl_xor(sum, 1);
        sum += __shfl_xor(sum, 2);
        float inv = 1.f / sum;
#pragma unroll
        for (int cc = 0; cc < 16; ++cc) p_s[row * 72 + j + cc] = f2b(e[cc] * inv);
    }
    __syncthreads();   // also fences s_s reads; s_s reused as O stage below

    // O = P V ; restage -> head-blocked [h][w][tok][d], coalesced uint4
    {
        u16* os = (u16*)s_s;   // [64][40]
#pragma unroll
        for (int nt = 0; nt < 2; ++nt) {
            f4_t acc = (f4_t){0.f, 0.f, 0.f, 0.f};
#pragma unroll
            for (int ks = 0; ks < 2; ++ks) {
                bx8 a = *(const bx8*)&p_s[(wave * 16 + l16) * 72 + ks * 32 + quad * 8];
                bx8 b = *(const bx8*)&vT[(nt * 16 + l16) * 72 + ks * 32 + quad * 8];
                acc = __builtin_amdgcn_mfma_f32_16x16x32_bf16(a, b, acc, 0, 0, 0);
            }
#pragma unroll
            for (int i = 0; i < 4; ++i)
                os[(wave * 16 + quad * 4 + i) * 40 + nt * 16 + l16] =
                    f2b(acc[i]);
        }
        __syncthreads();
        int tok = tid >> 2, d8 = (tid & 3) * 8;
        uint4 v = *(const uint4*)&os[tok * 40 + d8];
        *(uint4*)(attn_out + ((((size_t)h << 10) + w) << 11) + tid * 8) = v;
    }
}

extern "C" void kernel_launch(void* const* d_in, const int* in_sizes, int n_in,
                              void* d_out, int out_size, void* d_ws,
                              size_t ws_size, hipStream_t stream) {
    const float* x      = (const float*)d_in[0];
    const float* mask   = (const float*)d_in[1];
    const float* qkv_w  = (const float*)d_in[2];
    const float* qkv_b  = (const float*)d_in[3];
    const float* proj_w = (const float*)d_in[4];
    const float* proj_b = (const float*)d_in[5];
    const float* bias_t = (const float*)d_in[6];
    const int*   rel    = (const int*)d_in[7];
    float* out = (float*)d_out;

    char* ws = (char*)d_ws;
    u16* Wt1 = (u16*)ws;      ws += (size_t)1536 * 512 * 2;   // qkv_w^T bf16
    u16* Wt2 = (u16*)ws;      ws += (size_t)512 * 512 * 2;    // proj_w^T bf16
    float* biasf = (float*)ws; ws += (size_t)16 * 64 * 64 * 4; // bias_full
    u16* qkv = (u16*)ws;      ws += 3 * QKV_ELEMS * 2;        // Q,K,V planes
    u16* attn = (u16*)ws;     ws += QKV_ELEMS * 2;            // attn out bf16
    u16* xb = attn;  // alias: x_bf16 used only before attn_out is written

    cvt_k<<<16384, 256, 0, stream>>>(x, xb);   // 65536*512 / (256*8)
    wt_k<<<3072, 256, 0, stream>>>(qkv_w, Wt1, 512, 1536);
    wt_k<<<1024, 256, 0, stream>>>(proj_w, Wt2, 512, 512);
    bias_k<<<256, 256, 0, stream>>>(bias_t, rel, biasf);
    // QKV projection: M=65536, N=1536, K=512 (256x256 tiles, 6x256 grid)
    gemm256_k<0><<<1536, 512, 131072, stream>>>(xb, Wt1, qkv_b, qkv);
    // window attention: 1024 windows x 16 heads
    attn_k<<<16384, 256, 0, stream>>>(qkv, mask, biasf, attn);
    // output projection: M=65536, N=512, K=512 (2x256 grid)
    gemm256_k<1><<<512, 512, 131072, stream>>>(attn, Wt2, proj_b, out);
}

// Round 2
// 483.708 us; speedup vs baseline: 1.1358x; 1.0573x over previous
//
#include <hip/hip_runtime.h>
#include <hip/hip_bf16.h>

// ---------------------------------------------------------------------------
// Swin window MSA, MI355X/gfx950.
// R6: fix the T2 LDS swizzle. 64 B rows => bank slot = (row&1, chunk);
// R5's g(row)=row&3 only redistributed the parity bit (4-way conflicts
// remained, SQ_LDS_BANK_CONFLICT 1.1e7). New g(row)=(row>>1)&3 spreads each
// 16-lane quarter-wave across all 8 four-bank slots exactly twice (2-way is
// free, m136). Same permutation on the pre-swizzled global source and the
// ds_read address (both-sides-or-neither).
// Structure (R5): 256x256 tile, 8 waves (2Mx4N), BK=32, 4-slot LDS ring,
// counted vmcnt(8), setprio around MFMA clusters, XCD-bijective swizzle.
// qkv planes: [which][w][h][tok][d]. attn out: head-blocked [h][w][tok][d].
// ---------------------------------------------------------------------------

typedef unsigned short u16;
typedef __bf16 bx8 __attribute__((ext_vector_type(8)));
typedef float f4_t __attribute__((ext_vector_type(4)));

#define QKV_ELEMS 33554432ull        // 1024*16*64*32 per Q/K/V plane
#define SCALE 0.17677669529663687f   // 32^-0.5

static __device__ __forceinline__ u16 f2b(float f) {
    return __builtin_bit_cast(u16, (__bf16)f);
}

typedef const unsigned int __attribute__((address_space(1)))* gas_t;
typedef unsigned int __attribute__((address_space(3)))* las_t;
static __device__ __forceinline__ void glds16(const void* g, void* l) {
    __builtin_amdgcn_global_load_lds((gas_t)g, (las_t)l, 16, 0, 0);
}

// ---- prep: x fp32 -> bf16 (8 elems/thread) --------------------------------
__global__ void cvt_k(const float* __restrict__ X, u16* __restrict__ Xb) {
    size_t i = ((size_t)blockIdx.x * 256 + threadIdx.x) * 8;
    float4 v0 = *(const float4*)(X + i);
    float4 v1 = *(const float4*)(X + i + 4);
    ushort4 p0, p1;
    p0.x = f2b(v0.x); p0.y = f2b(v0.y); p0.z = f2b(v0.z); p0.w = f2b(v0.w);
    p1.x = f2b(v1.x); p1.y = f2b(v1.y); p1.z = f2b(v1.z); p1.w = f2b(v1.w);
    *(ushort4*)(Xb + i) = p0;
    *(ushort4*)(Xb + i + 4) = p1;
}

// ---- prep: W (K x N fp32) -> Wt (N x K bf16) ------------------------------
__global__ void wt_k(const float* __restrict__ W, u16* __restrict__ Wt,
                     int K, int N) {
    int idx = blockIdx.x * 256 + threadIdx.x;
    if (idx >= N * K) return;
    int n = idx / K, k = idx - n * K;
    Wt[idx] = f2b(W[(size_t)k * N + n]);
}

// ---- prep: bias_full[h][q][k] = bias_table[rel_index[q*64+k]][h] ----------
__global__ void bias_k(const float* __restrict__ bias_table,
                       const int* __restrict__ rel_index,
                       float* __restrict__ bias_full) {
    int idx = blockIdx.x * 256 + threadIdx.x;   // 16*4096
    int h = idx >> 12, rc = idx & 4095;
    bias_full[idx] = bias_table[rel_index[rc] * 16 + h];
}

// ---- 256x256-tile phase-interleaved GEMM ----------------------------------
// C = A @ Bt^T (+bias), K=512 fixed (NT=16 K-tiles of 32).
// MODE 0: A = xb row-major MxK; out -> QKV planes bf16.
// MODE 1: A = attn head-blocked [h][w][tok][32] (plane h == K-tile h);
//         out -> fp32 rows (N=512).

// one MFMA sub-cluster: a-frag x 4 b-frags
#define MF(av, mt)                                                            \
    acc[mt][0] = __builtin_amdgcn_mfma_f32_16x16x32_bf16(av, b0, acc[mt][0],  \
                                                         0, 0, 0);            \
    acc[mt][1] = __builtin_amdgcn_mfma_f32_16x16x32_bf16(av, b1, acc[mt][1],  \
                                                         0, 0, 0);            \
    acc[mt][2] = __builtin_amdgcn_mfma_f32_16x16x32_bf16(av, b2, acc[mt][2],  \
                                                         0, 0, 0);            \
    acc[mt][3] = __builtin_amdgcn_mfma_f32_16x16x32_bf16(av, b3, acc[mt][3],  \
                                                         0, 0, 0);

// one K-tile = 2 phases. vmcnt ONLY at the tile boundary (phase 2), counted.
#define TILE_STEP(T, DOSTAGE, VMC)                                            \
    {                                                                         \
        const char* aT = ldsA + ((T) & 3) * 16384 + wm * 8192 + foff;         \
        const char* bT = ldsB + ((T) & 3) * 16384 + wn * 4096 + foff;         \
        bx8 b0 = *(const bx8*)(bT);                                           \
        bx8 b1 = *(const bx8*)(bT + 1024);                                    \
        bx8 b2 = *(const bx8*)(bT + 2048);                                    \
        bx8 b3 = *(const bx8*)(bT + 3072);                                    \
        bx8 a0 = *(const bx8*)(aT);                                           \
        bx8 a1 = *(const bx8*)(aT + 1024);                                    \
        bx8 a2 = *(const bx8*)(aT + 2048);                                    \
        bx8 a3 = *(const bx8*)(aT + 3072);                                    \
        if (DOSTAGE) STAGE_A((T) + 3);                                        \
        __builtin_amdgcn_s_barrier();                                         \
        __builtin_amdgcn_s_setprio(1);                                        \
        MF(a0, 0) MF(a1, 1) MF(a2, 2) MF(a3, 3)                               \
        __builtin_amdgcn_s_setprio(0);                                        \
        __builtin_amdgcn_s_barrier();                                         \
        bx8 a4 = *(const bx8*)(aT + 4096);                                    \
        bx8 a5 = *(const bx8*)(aT + 5120);                                    \
        bx8 a6 = *(const bx8*)(aT + 6144);                                    \
        bx8 a7 = *(const bx8*)(aT + 7168);                                    \
        if (DOSTAGE) STAGE_B((T) + 3);                                        \
        if ((VMC) == 8) asm volatile("s_waitcnt vmcnt(8)" ::: "memory");      \
        else if ((VMC) == 4) asm volatile("s_waitcnt vmcnt(4)" ::: "memory"); \
        else if ((VMC) == 0) asm volatile("s_waitcnt vmcnt(0)" ::: "memory"); \
        __builtin_amdgcn_s_barrier();                                         \
        __builtin_amdgcn_s_setprio(1);                                        \
        MF(a4, 4) MF(a5, 5) MF(a6, 6) MF(a7, 7)                               \
        __builtin_amdgcn_s_setprio(0);                                        \
        __builtin_amdgcn_s_barrier();                                         \
    }

template <int MODE>
__global__ __launch_bounds__(512, 2) void gemm256_k(
    const u16* __restrict__ A, const u16* __restrict__ Bt,
    const float* __restrict__ bias, void* __restrict__ Out) {
    extern __shared__ __align__(16) char smem[];   // 131072 B dynamic
    const int tid = threadIdx.x;
    const int wave = tid >> 6, lane = tid & 63;
    const int l16 = lane & 15, quad = lane >> 4;
    const int wm = wave >> 2, wn = wave & 3;       // 2M x 4N wave grid

    // T1: bijective XCD swizzle (nwg % 8 == 0), mtile-major per chunk
    const int NT_COL = (MODE == 0) ? 6 : 2;
    const int NWG = (MODE == 0) ? 1536 : 512;
    const int bid = blockIdx.x;
    const int swz = (bid & 7) * (NWG >> 3) + (bid >> 3);
    const int m0 = (swz / NT_COL) << 8;
    const int n0 = (swz % NT_COL) << 8;

    char* const ldsA = smem;            // 4 slots x 16 KB
    char* const ldsB = smem + 65536;    // 4 slots x 16 KB

    // staging: per call (c=0/1) 512 threads cover 128 rows x 64 B.
    // HW lands lane l at base + l*16 -> row 16*wave + (l>>2), chunk l&3.
    // T2: LDS[row][c] = global[row][c ^ g(row&15)], g(r) = (r>>1)&3.
    // (row&1 is already a bank bit at 64 B stride; only bits [2:1] of the
    //  row can break same-parity aliasing.)
    const int lr = lane >> 2, lc = lane & 3;
    const int swzc = (lc ^ ((lr >> 1) & 3)) * 8;   // elems
    const int stoff = wave * 1024;                 // wave-uniform LDS base

    const u16* Asrc0;
    const u16* Asrc1;
    if (MODE == 0) {
        const int r0 = m0 + wave * 16 + lr;
        Asrc0 = A + (size_t)r0 * 512 + swzc;
        Asrc1 = Asrc0 + (size_t)128 * 512;
    } else {
        const int r0 = m0 + wave * 16 + lr, r1 = r0 + 128;
        Asrc0 = A + (size_t)(r0 >> 6) * 2048 + (r0 & 63) * 32 + swzc;
        Asrc1 = A + (size_t)(r1 >> 6) * 2048 + (r1 & 63) * 32 + swzc;
    }
    const u16* Bsrc0 = Bt + (size_t)(n0 + wave * 16 + lr) * 512 + swzc;
    const u16* Bsrc1 = Bsrc0 + (size_t)128 * 512;

    auto STAGE_A = [&](int T) {
        char* d = ldsA + (T & 3) * 16384 + stoff;
        if (MODE == 0) {
            glds16(Asrc0 + T * 32, d);
            glds16(Asrc1 + T * 32, d + 8192);
        } else {
            glds16(Asrc0 + (size_t)T * 2097152, d);
            glds16(Asrc1 + (size_t)T * 2097152, d + 8192);
        }
    };
    auto STAGE_B = [&](int T) {
        char* d = ldsB + (T & 3) * 16384 + stoff;
        glds16(Bsrc0 + T * 32, d);
        glds16(Bsrc1 + T * 32, d + 8192);
    };

    // frag read: row = (16-row block)*16 + l16, chunk = quad ^ g(l16)
    const int foff = l16 * 64 + ((quad ^ ((l16 >> 1) & 3)) * 16);

    f4_t acc[8][4];
#pragma unroll
    for (int i = 0; i < 8; ++i)
#pragma unroll
        for (int j = 0; j < 4; ++j) acc[i][j] = (f4_t){0.f, 0.f, 0.f, 0.f};

    // prologue: 3 K-tiles staged; vmcnt(8) retires tile 0 (and A1,B1)
    STAGE_A(0); STAGE_B(0); STAGE_A(1); STAGE_B(1); STAGE_A(2); STAGE_B(2);
    asm volatile("s_waitcnt vmcnt(8)" ::: "memory");
    __builtin_amdgcn_s_barrier();

    for (int T = 0; T < 13; ++T) TILE_STEP(T, true, 8);
    TILE_STEP(13, false, 4);
    TILE_STEP(14, false, 0);
    TILE_STEP(15, false, -1);

    float bv[4];
#pragma unroll
    for (int nt = 0; nt < 4; ++nt) bv[nt] = bias[n0 + wn * 64 + nt * 16 + l16];

    if (MODE == 0) {
        // epilogue: LDS restage -> QKV planes, 1024 B/wave contiguous stores.
        // column layout is [head][which][d]: 96 = 3*32 cols per head.
        u16* c_s = (u16*)smem;          // [128][264] bf16
        u16* qkvp = (u16*)Out;
        const int cg = n0 + wave * 32;
        const int hh = cg / 96;
        const int which = (cg - hh * 96) >> 5;
        u16* plane = qkvp + (size_t)which * QKV_ELEMS + (size_t)hh * 2048;
#pragma unroll
        for (int p = 0; p < 2; ++p) {
            if (wm == p) {
#pragma unroll
                for (int mt = 0; mt < 8; ++mt)
#pragma unroll
                    for (int nt = 0; nt < 4; ++nt)
#pragma unroll
                        for (int i = 0; i < 4; ++i)
                            c_s[(mt * 16 + quad * 4 + i) * 264 +
                                wn * 64 + nt * 16 + l16] =
                                f2b(acc[mt][nt][i] + bv[nt]);
            }
            __syncthreads();
#pragma unroll
            for (int j = 0; j < 8; ++j) {
                int row = j * 16 + (lane >> 2);
                int gm = m0 + p * 128 + row;
                int w_win = gm >> 6, tok = gm & 63;
                uint4 v = *(const uint4*)&c_s[row * 264 + wave * 32 +
                                              (lane & 3) * 8];
                *(uint4*)(plane + (size_t)w_win * 32768 + tok * 32 +
                          (lane & 3) * 8) = v;
            }
            __syncthreads();
        }
    } else {
        // epilogue: fp32 rows, 4 passes of 64 rows, 1024 B/wave stores
        float* c_sf = (float*)smem;     // [64][264] fp32
        float* Of = (float*)Out;
#pragma unroll
        for (int p = 0; p < 4; ++p) {
            if (wm == (p >> 1)) {
                const int mtb = (p & 1) * 4;
#pragma unroll
                for (int mt2 = 0; mt2 < 4; ++mt2)
#pragma unroll
                    for (int nt = 0; nt < 4; ++nt)
#pragma unroll
                        for (int i = 0; i < 4; ++i)
                            c_sf[(mt2 * 16 + quad * 4 + i) * 264 +
                                 wn * 64 + nt * 16 + l16] =
                                acc[mtb + mt2][nt][i] + bv[nt];
            }
            __syncthreads();
#pragma unroll
            for (int j = 0; j < 8; ++j) {
                int flat = tid + 512 * j;           // 64 rows x 64 float4
                int r = flat >> 6, c4 = (flat & 63) * 4;
                float4 v = *(const float4*)&c_sf[r * 264 + c4];
                *(float4*)&Of[(size_t)(m0 + p * 64 + r) * 512 + n0 + c4] = v;
            }
            __syncthreads();
        }
    }
}

// ---- attention: 1 block per (window, head), 4 waves -----------------------
__global__ __launch_bounds__(256) void attn_k(
    const u16* __restrict__ qkv, const float* __restrict__ mask,
    const float* __restrict__ biasf, u16* __restrict__ attn_out) {
    const int bx = blockIdx.x;
    const int w = bx >> 4, h = bx & 15;
    const int wmk = w & 255;  // mask window = b % 256
    const int tid = threadIdx.x;
    const int wave = tid >> 6, lane = tid & 63;
    const int quad = lane >> 4, l16 = lane & 15;

    __shared__ alignas(16) u16 q_s[64 * 40];
    __shared__ alignas(16) u16 k_s[64 * 40];
    __shared__ alignas(16) u16 vT[32 * 72];   // vT[d][tok]
    __shared__ alignas(16) float s_s[64 * 68];
    __shared__ alignas(16) u16 p_s[64 * 72];

    const size_t base = (size_t)((w << 4) + h) * 2048;  // 64*32 per (w,h)
    {
        int tok = tid >> 2, d0 = (tid & 3) * 8;
        uint4 qv = *(const uint4*)(qkv + base + tid * 8);
        *(uint4*)&q_s[tok * 40 + d0] = qv;
        uint4 kv = *(const uint4*)(qkv + QKV_ELEMS + base + tid * 8);
        *(uint4*)&k_s[tok * 40 + d0] = kv;
        uint4 vv = *(const uint4*)(qkv + 2 * QKV_ELEMS + base + tid * 8);
        const u16* pv = (const u16*)&vv;
#pragma unroll
        for (int j = 0; j < 8; ++j) vT[(d0 + j) * 72 + tok] = pv[j];
    }
    __syncthreads();

    // S = Q K^T * scale + bias + mask  (wave -> 16-row strip)
    {
        bx8 a = *(const bx8*)&q_s[(wave * 16 + l16) * 40 + quad * 8];
#pragma unroll
        for (int nt = 0; nt < 4; ++nt) {
            bx8 b = *(const bx8*)&k_s[(nt * 16 + l16) * 40 + quad * 8];
            f4_t acc = (f4_t){0.f, 0.f, 0.f, 0.f};
            acc = __builtin_amdgcn_mfma_f32_16x16x32_bf16(a, b, acc, 0, 0, 0);
#pragma unroll
            for (int i = 0; i < 4; ++i) {
                int r = wave * 16 + quad * 4 + i;
                int c = nt * 16 + l16;
                float s = acc[i] * SCALE + biasf[(h << 12) + (r << 6) + c] +
                          mask[((size_t)wmk * 64 + r) * 64 + c];
                s_s[r * 68 + c] = s;
            }
        }
    }
    __syncthreads();

    // row softmax: 4 threads per row, 16 cols each, shuffle-reduce
    {
        int row = tid >> 2, j = (tid & 3) * 16;
        float mx = -1e30f;
#pragma unroll
        for (int cc = 0; cc < 16; ++cc) mx = fmaxf(mx, s_s[row * 68 + j + cc]);
        mx = fmaxf(mx, __shfl_xor(mx, 1));
        mx = fmaxf(mx, __shfl_xor(mx, 2));
        float e[16], sum = 0.f;
#pragma unroll
        for (int cc = 0; cc < 16; ++cc) {
            e[cc] = __expf(s_s[row * 68 + j + cc] - mx);
            sum += e[cc];
        }
        sum += __shfl_xor(sum, 1);
        sum += __shfl_xor(sum, 2);
        float inv = 1.f / sum;
#pragma unroll
        for (int cc = 0; cc < 16; ++cc) p_s[row * 72 + j + cc] = f2b(e[cc] * inv);
    }
    __syncthreads();   // also fences s_s reads; s_s reused as O stage below

    // O = P V ; restage -> head-blocked [h][w][tok][d], coalesced uint4
    {
        u16* os = (u16*)s_s;   // [64][40]
#pragma unroll
        for (int nt = 0; nt < 2; ++nt) {
            f4_t acc = (f4_t){0.f, 0.f, 0.f, 0.f};
#pragma unroll
            for (int ks = 0; ks < 2; ++ks) {
                bx8 a = *(const bx8*)&p_s[(wave * 16 + l16) * 72 + ks * 32 + quad * 8];
                bx8 b = *(const bx8*)&vT[(nt * 16 + l16) * 72 + ks * 32 + quad * 8];
                acc = __builtin_amdgcn_mfma_f32_16x16x32_bf16(a, b, acc, 0, 0, 0);
            }
#pragma unroll
            for (int i = 0; i < 4; ++i)
                os[(wave * 16 + quad * 4 + i) * 40 + nt * 16 + l16] =
                    f2b(acc[i]);
        }
        __syncthreads();
        int tok = tid >> 2, d8 = (tid & 3) * 8;
        uint4 v = *(const uint4*)&os[tok * 40 + d8];
        *(uint4*)(attn_out + ((((size_t)h << 10) + w) << 11) + tid * 8) = v;
    }
}

extern "C" void kernel_launch(void* const* d_in, const int* in_sizes, int n_in,
                              void* d_out, int out_size, void* d_ws,
                              size_t ws_size, hipStream_t stream) {
    const float* x      = (const float*)d_in[0];
    const float* mask   = (const float*)d_in[1];
    const float* qkv_w  = (const float*)d_in[2];
    const float* qkv_b  = (const float*)d_in[3];
    const float* proj_w = (const float*)d_in[4];
    const float* proj_b = (const float*)d_in[5];
    const float* bias_t = (const float*)d_in[6];
    const int*   rel    = (const int*)d_in[7];
    float* out = (float*)d_out;

    char* ws = (char*)d_ws;
    u16* Wt1 = (u16*)ws;      ws += (size_t)1536 * 512 * 2;   // qkv_w^T bf16
    u16* Wt2 = (u16*)ws;      ws += (size_t)512 * 512 * 2;    // proj_w^T bf16
    float* biasf = (float*)ws; ws += (size_t)16 * 64 * 64 * 4; // bias_full
    u16* qkv = (u16*)ws;      ws += 3 * QKV_ELEMS * 2;        // Q,K,V planes
    u16* attn = (u16*)ws;     ws += QKV_ELEMS * 2;            // attn out bf16
    u16* xb = attn;  // alias: x_bf16 used only before attn_out is written

    cvt_k<<<16384, 256, 0, stream>>>(x, xb);   // 65536*512 / (256*8)
    wt_k<<<3072, 256, 0, stream>>>(qkv_w, Wt1, 512, 1536);
    wt_k<<<1024, 256, 0, stream>>>(proj_w, Wt2, 512, 512);
    bias_k<<<256, 256, 0, stream>>>(bias_t, rel, biasf);
    // QKV projection: M=65536, N=1536, K=512 (256x256 tiles, 6x256 grid)
    gemm256_k<0><<<1536, 512, 131072, stream>>>(xb, Wt1, qkv_b, qkv);
    // window attention: 1024 windows x 16 heads
    attn_k<<<16384, 256, 0, stream>>>(qkv, mask, biasf, attn);
    // output projection: M=65536, N=512, K=512 (2x256 grid)
    gemm256_k<1><<<512, 512, 131072, stream>>>(attn, Wt2, proj_b, out);
}